// Round 6
// baseline (476.404 us; speedup 1.0000x reference)
//
#include <hip/hip_runtime.h>
#include <hip/hip_bf16.h>

// minLSTM: pre = x @ W^T + b (M=32768, N=1536, K=512), log-space gates,
// chunked log-space scan over L=4096 per (n,h), out = exp(log_h).
// ALL log-domain values are in LOG2 units (v_exp/v_log are base-2 native).
// Gate math: sigma-sum identity (3 exp + 4 log per position).
// SINGLE-PASS: gemm_gates computes the GEMM, gate math, per-chunk scan AND
// the cross-chunk carry via decoupled lookback (rocPRIM-style), then writes
// exp2(log_h) directly. No plv materialization (saves 128 MB HBM), no
// scan_apply kernel. Chunk transform r->la(A+r,B); aggregate published
// state 1, inclusive prefix state 2; lookback folds backward:
//   P = P∘T : A_P += A_T ; B_P = la(A_P_old + B_T, B_P).
// Deadlock-free: block (by,bx) waits only on (by-1..,bx) = strictly lower
// linear IDs (dispatched earlier). Flags zeroed per-launch via memsetAsync.
// Rounds 2-4 falsified: any fp32-A-in-GEMM scheme loses more than the
// 2-pass convert costs. Do not revisit.

#define H_DIM 512
#define LSEQ 4096
#define NBATCH 8
#define M_TOTAL (NBATCH * LSEQ)  // 32768

#define BM 128
#define BK 64

#define CS 128
#define NC 32            // LSEQ / CS

typedef __attribute__((ext_vector_type(8))) short short8;
typedef __attribute__((ext_vector_type(4))) float floatx4;
typedef __attribute__((ext_vector_type(4))) float float4v;
typedef _Float16 h2 __attribute__((ext_vector_type(2)));

#define NEG_BIG (-1.0e30f)
#define C_LOG2E 1.4426950408889634f
#define LOG2_HX0 (-19.931568569324174f)   // log2(1e-6)

__device__ __forceinline__ float exp2_hw(float x) {
#if __has_builtin(__builtin_amdgcn_exp2f)
    return __builtin_amdgcn_exp2f(x);     // v_exp_f32
#else
    return exp2f(x);
#endif
}

__device__ __forceinline__ float log2_hw(float x) {
#if __has_builtin(__builtin_amdgcn_logf)
    return __builtin_amdgcn_logf(x);      // v_log_f32 (base-2)
#else
    return log2f(x);
#endif
}

// log2(2^p + 2^q), robust for -inf-ish inputs
__device__ __forceinline__ float logaddexp2_f(float p, float q) {
    float m = fmaxf(p, q);
    float d = -fabsf(p - q);
    return m + log2_hw(1.0f + exp2_hw(d));
}

__device__ __forceinline__ float bf16u_to_f(unsigned short u) {
    unsigned int w = ((unsigned int)u) << 16;
    float f;
    __builtin_memcpy(&f, &w, 4);
    return f;
}

__device__ __forceinline__ unsigned short f_to_bf16u(float f) {
    __hip_bfloat16 h = __float2bfloat16(f);
    unsigned short u;
    __builtin_memcpy(&u, &h, 2);
    return u;
}

__device__ __forceinline__ void gload_lds16(const void* g, void* l) {
    __builtin_amdgcn_global_load_lds(
        (const __attribute__((address_space(1))) unsigned int*)g,
        (__attribute__((address_space(3))) unsigned int*)l, 16, 0, 0);
}

// ---------------------------------------------------------------------------
// Kernel 0: dtype detect (single block) + bias -> f32. Vectorized loads.
// fp32 data: low u16 halves uniform -> bf16-NaN exponent P=1/256,
// E[hits in 16384] = 64; bf16 N(0,1) data: 0 hits.
// ---------------------------------------------------------------------------
__global__ void detect_and_bias(const unsigned short* __restrict__ xu,
                                const void* __restrict__ bsrc,
                                int* __restrict__ flag,
                                float* __restrict__ bdst) {
    __shared__ int cnt;
    if (threadIdx.x == 0) cnt = 0;
    __syncthreads();
    const short8* x8 = (const short8*)xu;   // 16384 u16 = 2048 short8
    int local = 0;
    #pragma unroll
    for (int j = 0; j < 8; j++) {
        short8 v = x8[threadIdx.x + j * 256];
        #pragma unroll
        for (int e = 0; e < 8; e++) {
            unsigned short u = (unsigned short)v[e];
            if (((u >> 7) & 0xFF) == 0xFF) local++;
        }
    }
    if (local) atomicAdd(&cnt, local);
    __syncthreads();
    int f = (cnt > 8) ? 1 : 0;
    if (threadIdx.x == 0) flag[0] = f;
    #pragma unroll
    for (int j = 0; j < 6; j++) {
        int i = threadIdx.x + j * 256;
        bdst[i] = f ? ((const float*)bsrc)[i]
                    : bf16u_to_f(((const unsigned short*)bsrc)[i]);
    }
}

// ---------------------------------------------------------------------------
// Kernel 0b: normalize x and W to bf16 (role by block range). Vector loads.
//   [0, 8192) -> x (16777216 elems), [8192, 8576) -> W (786432 elems)
// ---------------------------------------------------------------------------
__global__ __launch_bounds__(256)
void convert_inputs(const void* __restrict__ x, const void* __restrict__ W,
                    unsigned short* __restrict__ xc,
                    unsigned short* __restrict__ Wc,
                    const int* __restrict__ flag) {
    const int bx = blockIdx.x;
    const void* src;
    unsigned short* dst;
    int i;
    if (bx < 8192) { src = x; dst = xc; i = (bx * 256 + threadIdx.x) * 8; }
    else           { src = W; dst = Wc; i = ((bx - 8192) * 256 + threadIdx.x) * 8; }
    if (*flag) {
        const float4v* s4 = (const float4v*)((const float*)src + i);
        float4v a = s4[0], b = s4[1];
        short8 v;
        v[0] = (short)f_to_bf16u(a[0]); v[1] = (short)f_to_bf16u(a[1]);
        v[2] = (short)f_to_bf16u(a[2]); v[3] = (short)f_to_bf16u(a[3]);
        v[4] = (short)f_to_bf16u(b[0]); v[5] = (short)f_to_bf16u(b[1]);
        v[6] = (short)f_to_bf16u(b[2]); v[7] = (short)f_to_bf16u(b[3]);
        *(short8*)&dst[i] = v;
    } else {
        *(short8*)&dst[i] = *(const short8*)&((const short*)src)[i];
    }
}

// ---------------------------------------------------------------------------
// Kernel 1: fused GEMM + gates + single-pass scan + output.
// Block 256 = 4 waves (2x2), grid (256, 8): by=blockIdx.x (row block /
// chunk), bx=blockIdx.y (64-col group). global_load_lds staging, LDS XOR
// swizzle. After the K-loop: epilogue -> sc (LDS only); per-wave 32-t
// sub-scan -> sa/sb (LDS); wave 0 publishes aggregate (state1), lookback
// to build prefix, publishes inclusive (state2), derives r_start; all
// waves fold sub-summaries and replay 32 t, writing exp2(r) to out.
// ---------------------------------------------------------------------------
__global__ __launch_bounds__(256, 3)
void gemm_gates(const unsigned short* __restrict__ x,
                const unsigned short* __restrict__ W,
                const float* __restrict__ bias,
                float* __restrict__ aggA, float* __restrict__ aggB,
                float* __restrict__ incA, float* __restrict__ incB,
                int* __restrict__ flags,
                void* __restrict__ outv, const int* __restrict__ oflag) {
    __shared__ __align__(16) char ldsbuf[40960];
    short* Alds = (short*)ldsbuf;              // 16 KB during K-loop
    short* Blds = (short*)(ldsbuf + 16384);    // 24 KB during K-loop
    h2* sc = (h2*)ldsbuf;                      // 16 KB after K-loop (128t x 64h)
    float* sa = (float*)(ldsbuf + 32768);      // 1 KB sub-summary A
    float* sb = (float*)(ldsbuf + 33792);      // 1 KB sub-summary B
    float* carr = (float*)(ldsbuf + 34816);    // 256 B chunk-entry carry

    const int by = blockIdx.x;             // row block 0..255 (XCD = by%8)
    const int bx = blockIdx.y;             // col block 0..7 (64 cols/gate)
    const int tid = threadIdx.x;
    const int lane = tid & 63;
    const int w = tid >> 6;
    const int wr = (w >> 1) * 64;
    const int wc2 = w & 1;
    const int l8 = lane >> 3, s8 = lane & 7;
    const int sg = s8 ^ l8;                // swizzled global seg for staging
    const int fr = lane & 15;
    const int q = lane >> 4;

    const int R0 = by * BM;

    floatx4 acc[4][6];
    #pragma unroll
    for (int i = 0; i < 4; i++)
        #pragma unroll
        for (int j = 0; j < 6; j++)
            acc[i][j] = (floatx4){0.f, 0.f, 0.f, 0.f};

    const short* xg = (const short*)x;
    const short* wg = (const short*)W;

    for (int k0 = 0; k0 < H_DIM; k0 += BK) {
        __syncthreads();
        #pragma unroll
        for (int i = 0; i < 4; i++) {
            int c = w * 4 + i;
            const short* g = xg + (size_t)(R0 + c * 8 + l8) * H_DIM + k0 + sg * 8;
            gload_lds16(g, &Alds[c * 512]);
        }
        #pragma unroll
        for (int i = 0; i < 6; i++) {
            int c = w * 6 + i;
            int br = c * 8 + l8;
            int wrow = (br >> 6) * H_DIM + bx * 64 + (br & 63);
            const short* g = wg + (size_t)wrow * H_DIM + k0 + sg * 8;
            gload_lds16(g, &Blds[c * 512]);
        }
        __syncthreads();

        #pragma unroll
        for (int ks = 0; ks < 2; ks++) {
            const int s = ks * 4 + q;
            short8 af[4], bf[6];
            #pragma unroll
            for (int mt = 0; mt < 4; mt++) {
                int ar = wr + mt * 16 + fr;
                af[mt] = *(const short8*)&Alds[ar * BK + ((s ^ (ar & 7)) << 3)];
            }
            #pragma unroll
            for (int j = 0; j < 6; j++) {
                int nt = (j >> 1) * 4 + wc2 * 2 + (j & 1);
                int brr = nt * 16 + fr;
                bf[j] = *(const short8*)&Blds[brr * BK + ((s ^ (brr & 7)) << 3)];
            }
            #pragma unroll
            for (int mt = 0; mt < 4; mt++)
                #pragma unroll
                for (int j = 0; j < 6; j++)
                    acc[mt][j] = __builtin_amdgcn_mfma_f32_16x16x32_bf16(
                        af[mt], bf[j], acc[mt][j], 0, 0, 0);
        }
    }

    __syncthreads();   // staging LDS dead; reuse as sc

    // Epilogue: C/D layout col=lane&15, row=quad*4+reg [m89/m91].
    // sigma-sum form, all in log2 units. LDS only (no plv).
    const int tloc0 = wr + q * 4;
    #pragma unroll
    for (int jj = 0; jj < 2; jj++) {
        int hl = wc2 * 32 + jj * 16 + fr;
        int hcol = bx * 64 + hl;
        float bfv = bias[hcol];
        float biv = bias[H_DIM + hcol];
        float bhv = bias[2 * H_DIM + hcol];
        float bf2 = -bfv * C_LOG2E;        // fold bias into exp arg via fma
        float bi2 = -biv * C_LOG2E;
        #pragma unroll
        for (int mt = 0; mt < 4; mt++) {
            #pragma unroll
            for (int r = 0; r < 4; r++) {
                float ef = exp2_hw(fminf(fmaf(acc[mt][jj][r], -C_LOG2E, bf2), 126.0f));
                float ei = exp2_hw(fminf(fmaf(acc[mt][2 + jj][r], -C_LOG2E, bi2), 126.0f));
                float hp = acc[mt][4 + jj][r] + bhv;
                float eh = exp2_hw(fminf(-hp * C_LOG2E, 126.0f));
                float afv = 1.0f + ef, aiv = 1.0f + ei;
                float sfi = afv + aiv;
                float ls = log2_hw(sfi);
                float lf = log2_hw(aiv) - ls;                  // log2 f'
                float marg = (hp >= 0.0f) ? (hp + 0.5f) : (1.0f + eh);
                float lm = log2_hw(marg);
                float lg = (hp >= 0.0f) ? lm : -lm;            // log2 g
                float lv = (log2_hw(afv) - ls) + lg;           // log2 (i' g)
                h2 pk;
                pk[0] = (_Float16)lf;
                pk[1] = (_Float16)lv;
                sc[(tloc0 + mt * 16 + r) * 64 + hl] = pk;
            }
        }
    }

    __syncthreads();

    const int c = by & 31;
    const int fidx = by * 8 + bx;
    // Wave w scans t in [w*32, w*32+32) for col=lane -> LDS sub-summary.
    {
        float a = 0.f, bacc = NEG_BIG;
        const int t0 = w * 32;
        #pragma unroll 4
        for (int t = t0; t < t0 + 32; t++) {
            h2 p = sc[t * 64 + lane];
            float f = (float)p[0];
            bacc = logaddexp2_f(f + bacc, (float)p[1]);
            a += f;
        }
        sa[w * 64 + lane] = a;
        sb[w * 64 + lane] = bacc;
    }
    __syncthreads();

    if (w == 0) {
        // chunk aggregate (Ac, Bc) per col
        float Ac = sa[lane], Bc = sb[lane];
        #pragma unroll
        for (int s = 1; s < 4; s++) {
            float as = sa[s * 64 + lane], bs = sb[s * 64 + lane];
            Bc = logaddexp2_f(as + Bc, bs);
            Ac += as;
        }
        float r_start;
        if (c == 0) {
            incA[fidx * 64 + lane] = Ac;
            incB[fidx * 64 + lane] = Bc;
            __threadfence();
            if (lane == 0)
                __hip_atomic_store(&flags[fidx], 2, __ATOMIC_RELEASE,
                                   __HIP_MEMORY_SCOPE_AGENT);
            r_start = LOG2_HX0;
        } else {
            // publish aggregate first so successors can fold while we wait
            aggA[fidx * 64 + lane] = Ac;
            aggB[fidx * 64 + lane] = Bc;
            __threadfence();
            if (lane == 0)
                __hip_atomic_store(&flags[fidx], 1, __ATOMIC_RELEASE,
                                   __HIP_MEMORY_SCOPE_AGENT);
            // lookback: prefix transform P over chunks 0..c-1 (backward)
            float Ap = 0.f, Bp = NEG_BIG;
            int cp = c - 1;
            while (cp >= 0) {
                int f2 = fidx - (c - cp) * 8;    // (n*32+cp)*8 + bx
                int st;
                while ((st = __hip_atomic_load(&flags[f2], __ATOMIC_ACQUIRE,
                                               __HIP_MEMORY_SCOPE_AGENT)) == 0)
                    __builtin_amdgcn_s_sleep(2);
                if (st == 2) {
                    float At = incA[f2 * 64 + lane], Bt = incB[f2 * 64 + lane];
                    Bp = logaddexp2_f(Ap + Bt, Bp);
                    Ap += At;
                    break;
                } else {
                    float At = aggA[f2 * 64 + lane], Bt = aggB[f2 * 64 + lane];
                    Bp = logaddexp2_f(Ap + Bt, Bp);
                    Ap += At;
                    cp--;
                }
            }
            // own inclusive = T_c ∘ P
            incA[fidx * 64 + lane] = Ap + Ac;
            incB[fidx * 64 + lane] = logaddexp2_f(Ac + Bp, Bc);
            __threadfence();
            if (lane == 0)
                __hip_atomic_store(&flags[fidx], 2, __ATOMIC_RELEASE,
                                   __HIP_MEMORY_SCOPE_AGENT);
            r_start = logaddexp2_f(Ap + LOG2_HX0, Bp);
        }
        carr[lane] = r_start;
    }
    __syncthreads();

    // Replay: wave w starts from carr folded with sub-summaries 0..w-1,
    // then walks its 32 timesteps from sc, writing exp2(r) to out.
    {
        float r = carr[lane];
        #pragma unroll
        for (int s = 0; s < 4; s++) {
            if (s < w) {
                r = logaddexp2_f(sa[s * 64 + lane] + r, sb[s * 64 + lane]);
            }
        }
        const int t0 = w * 32;
        const size_t row0 = (size_t)by * BM + t0;     // = n*LSEQ + c*CS + t0
        const int col = bx * 64 + lane;
        if (*oflag) {
            float* of = (float*)outv;
            #pragma unroll 4
            for (int t = 0; t < 32; t++) {
                h2 p = sc[(t0 + t) * 64 + lane];
                r = logaddexp2_f((float)p[0] + r, (float)p[1]);
                of[(row0 + t) * H_DIM + col] = exp2_hw(r);
            }
        } else {
            unsigned short* ob = (unsigned short*)outv;
            #pragma unroll 4
            for (int t = 0; t < 32; t++) {
                h2 p = sc[(t0 + t) * 64 + lane];
                r = logaddexp2_f((float)p[0] + r, (float)p[1]);
                ob[(row0 + t) * H_DIM + col] = f_to_bf16u(exp2_hw(r));
            }
        }
    }
}

extern "C" void kernel_launch(void* const* d_in, const int* in_sizes, int n_in,
                              void* d_out, int out_size, void* d_ws, size_t ws_size,
                              hipStream_t stream) {
    const void* x = d_in[0];
    const void* W = d_in[1];
    const void* b = d_in[2];

    char* wsb = (char*)d_ws;
    int* flag            = (int*)wsb;                          // 16 B
    float* bconv         = (float*)(wsb + 16);                 // 6 KB
    unsigned short* xc   = (unsigned short*)(wsb + 16384);     // 32 MB
    unsigned short* Wc   = (unsigned short*)(wsb + 16384 + 33554432);  // 1.5 MB
    float* aggA          = (float*)(wsb + 36700160);           // 512 KB
    float* aggB          = (float*)(wsb + 36700160 + 524288);  // 512 KB
    float* incA          = (float*)(wsb + 36700160 + 1048576); // 512 KB
    float* incB          = (float*)(wsb + 36700160 + 1572864); // 512 KB
    int* flags           = (int*)(wsb + 36700160 + 2097152);   // 8 KB

    detect_and_bias<<<1, 256, 0, stream>>>((const unsigned short*)x, b, flag, bconv);
    convert_inputs<<<8576, 256, 0, stream>>>(x, W, xc, Wc, flag);
    hipMemsetAsync(flags, 0, 2048 * sizeof(int), stream);

    dim3 g1(M_TOTAL / BM, H_DIM / 64);   // (256, 8): by on x for XCD share
    gemm_gates<<<g1, 256, 0, stream>>>(xc, Wc, bconv, aggA, aggB, incA, incB,
                                       flags, d_out, flag);
}